// Round 4
// baseline (196.023 us; speedup 1.0000x reference)
//
#include <hip/hip_runtime.h>
#include <math.h>

namespace {
constexpr int BATCH = 4;
constexpr int DDIM  = 128;
constexpr int HDIM  = 192;
constexpr int WDIM  = 192;
constexpr long long NTOT = (long long)BATCH * DDIM * HDIM * WDIM; // 18,874,368
constexpr int NDSC  = 4 * 1 * 8 * 12 * 12;                        // 4608

constexpr int HT     = 4;               // h rows per (one-wave) block
constexpr int DT     = 32;              // d planes per block
constexpr int ROWS   = HT + 2;          // 6 slab rows: h0-1 .. h0+HT (clamped)
constexpr int SLABF  = ROWS * WDIM;     // 1152 floats per tensor per slab
constexpr int SLAB2  = 2 * SLABF;       // 2304 floats per slab = 9216 B
constexpr int RING   = 5;               // 5-slab ring -> lead = 3 iterations
constexpr int UNITS  = (SLAB2 * 4) / 1024; // 9 DMA units (1024 B each) per slab
constexpr int BLOCKV = 64;              // ONE wave per block: no barriers at all
constexpr int NHT    = HDIM / HT;       // 48
constexpr int NDC    = DDIM / DT;       // 4
constexpr int GRIDV  = BATCH * NDC * NHT; // 768 = exactly 3 blocks/CU, one round
constexpr int PLSTR  = HDIM * WDIM;     // 36,864 floats per plane
constexpr int BLOCKF = 256;
}

// gd contribution: (|dy|*s - |dp|*s)^2 == s^2 * (|dy|-|dp|)^2, s2 in {1, 0.25}
#define GTERM(dy, dp, s2) { float t0_ = fabsf(dy) - fabsf(dp); gd = fmaf(t0_ * t0_, (s2), gd); }

// Stage one plane-slab as 9 flat 1024B units (64 lanes x 16B -- the HW-verified
// global_load_lds width). Per-lane SOURCE addresses (sr[]) carry the row/tensor
// decode + h-clamping; the LDS destination is linear and wave-uniform.
#define STAGE(buf, plane)                                                       \
    {                                                                           \
        const int poff_ = (plane) * PLSTR;                                      \
        _Pragma("unroll")                                                       \
        for (int k = 0; k < UNITS; ++k) {                                       \
            __builtin_amdgcn_global_load_lds(                                   \
                (const __attribute__((address_space(1))) void*)(sr[k] + poff_), \
                (__attribute__((address_space(3))) void*)(&slab[buf][k * 256]), \
                16, 0, 0);                                                      \
        }                                                                       \
    }

__global__ __launch_bounds__(BLOCKV) void vol_kernel(const float* __restrict__ p,
                                                     const float* __restrict__ y,
                                                     float* __restrict__ part) {
    __shared__ float slab[RING][SLAB2];   // 46,080 B -> 3 blocks (3 waves) per CU

    const int lane = threadIdx.x;         // 0..63
    const int r    = lane >> 4;           // 0..3   (row within tile)
    const int i16  = lane & 15;           // 0..15  (16 threads per row)
    const int w0   = i16 * 12;            // 12 consecutive w per thread

    // XCD-bijective swizzle (768 % 8 == 0): adjacent h-tiles share halo rows
    // and land on the same XCD's L2. part[] is indexed by the ORIGINAL id.
    const int blk0 = blockIdx.x;
    const int swz  = (blk0 & 7) * (GRIDV / 8) + (blk0 >> 3);
    const int ht   = swz % NHT;
    const int rs   = swz / NHT;
    const int dc   = rs & (NDC - 1);
    const int b    = rs >> 2;
    const int h0   = ht * HT;
    const int d0   = dc * DT;
    const int h    = h0 + r;

    // ---- per-lane DMA source descriptors (at plane 0) for the 9 units ----
    // unit k covers slab floats [k*256, k*256+256); lane L owns fi = k*256+L*4.
    // fi < SLABF -> tensor y else p; 16B chunks never straddle a row (192%4==0)
    // nor the y/p boundary (1152 = unit 4, lane 32 exactly).
    const float* sr[UNITS];
    #pragma unroll
    for (int k = 0; k < UNITS; ++k) {
        const int fi  = k * 256 + lane * 4;
        const int ts  = fi >= SLABF;
        const int fj  = ts ? fi - SLABF : fi;
        const int row = fj / WDIM;
        const int col = fj - row * WDIM;
        int hrow = h0 - 1 + row;
        hrow = hrow < 0 ? 0 : (hrow > HDIM - 1 ? HDIM - 1 : hrow);
        sr[k] = (ts ? p : y) + (b * DDIM * HDIM + hrow) * WDIM + col;
    }

    // ---- prologue: per-thread centers of planes clamp(d0-1) and d0 into regs ----
    float4 ym[2][3], yc[2][3];
    {
        const int pmz = d0 ? d0 - 1 : 0;
        const int om = ((b * DDIM + pmz) * HDIM + h) * WDIM + w0;
        const int oc = ((b * DDIM + d0 ) * HDIM + h) * WDIM + w0;
        #pragma unroll
        for (int g = 0; g < 3; ++g) {
            ym[0][g] = *(const float4*)(y + om + 4 * g);
            ym[1][g] = *(const float4*)(p + om + 4 * g);
            yc[0][g] = *(const float4*)(y + oc + 4 * g);
            yc[1][g] = *(const float4*)(p + oc + 4 * g);
        }
    }
    // ---- prologue: stage slabs for planes d0..d0+3 (d0+3 <= 99 < 128) ----
    STAGE(0, d0);
    STAGE(1, d0 + 1);
    STAGE(2, d0 + 2);
    STAGE(3, d0 + 3);

    float l1 = 0.f, gd = 0.f;
    const float s2h  = (h == 0 || h == HDIM - 1) ? 1.f : 0.25f;
    const float s2w0 = (i16 == 0)  ? 1.f : 0.25f;
    const float s2w3 = (i16 == 15) ? 1.f : 0.25f;

    int cur = 0;                          // buffer of plane e (== i mod 5)
    #pragma unroll 1
    for (int i = 0; i < DT; ++i) {
        const int e = d0 + i;
        // Counted wait: allow the newest 2 batches (planes e+2, e+3; 9 loads
        // each) to stay in flight; everything older (incl. plane e+1, read as
        // 'ns') is complete. Tail: 1 then 0 batches remain.
        if (i < DT - 2)       { asm volatile("s_waitcnt vmcnt(18)" ::: "memory"); }
        else if (i == DT - 2) { asm volatile("s_waitcnt vmcnt(9)"  ::: "memory"); }
        else                  { asm volatile("s_waitcnt vmcnt(0)"  ::: "memory"); }
        __builtin_amdgcn_sched_barrier(0);

        // Issue next stage IMMEDIATELY (T14): target buffer held plane e-1,
        // whose ds_reads were consumed last iteration (same wave -> no race).
        // Lead for a slab = 3 iterations + this iteration's compute.
        if (i <= DT - 4) {
            int pl = e + 4; if (pl > DDIM - 1) pl = DDIM - 1;
            const int stg = cur ? cur - 1 : RING - 1;   // (i+4) % RING
            STAGE(stg, pl);
        }

        const int nx = (cur + 1 == RING) ? 0 : cur + 1;
        const float* cs = &slab[cur][0];  // plane e   (h/w neighbors)
        const float* ns = &slab[nx][0];   // plane e+1 (centers -> next yc)
        const float s2d = (e == 0 || e == DDIM - 1) ? 1.f : 0.25f;

        const int rowc = (r + 1) * WDIM;
        const float wlY = cs[rowc + (i16 ? w0 - 1 : 0)];
        const float wrY = cs[rowc + (i16 < 15 ? w0 + 12 : WDIM - 1)];
        const float wlP = cs[SLABF + rowc + (i16 ? w0 - 1 : 0)];
        const float wrP = cs[SLABF + rowc + (i16 < 15 ? w0 + 12 : WDIM - 1)];

        float4 cn[2][3];
        #pragma unroll
        for (int g = 0; g < 3; ++g) {
            const int off = w0 + 4 * g;
            const float4 cny = *(const float4*)&ns[rowc + off];
            const float4 cnp = *(const float4*)&ns[SLABF + rowc + off];
            const float4 hmy = *(const float4*)&cs[r * WDIM + off];
            const float4 hpy = *(const float4*)&cs[(r + 2) * WDIM + off];
            const float4 hmp = *(const float4*)&cs[SLABF + r * WDIM + off];
            const float4 hpp = *(const float4*)&cs[SLABF + (r + 2) * WDIM + off];
            cn[0][g] = cny; cn[1][g] = cnp;
            const float4 ay = yc[0][g], ap = yc[1][g];
            const float4 my = ym[0][g], mp = ym[1][g];

            // L1
            l1 += fabsf(ay.x - ap.x) + fabsf(ay.y - ap.y)
                + fabsf(ay.z - ap.z) + fabsf(ay.w - ap.w);
            // H axis
            GTERM(hpy.x - hmy.x, hpp.x - hmp.x, s2h);
            GTERM(hpy.y - hmy.y, hpp.y - hmp.y, s2h);
            GTERM(hpy.z - hmy.z, hpp.z - hmp.z, s2h);
            GTERM(hpy.w - hmy.w, hpp.w - hmp.w, s2h);
            // D axis (register pipeline + next-slab centers)
            GTERM(cny.x - my.x, cnp.x - mp.x, s2d);
            GTERM(cny.y - my.y, cnp.y - mp.y, s2d);
            GTERM(cny.z - my.z, cnp.z - mp.z, s2d);
            GTERM(cny.w - my.w, cnp.w - mp.w, s2d);
        }
        // W axis: 12 consecutive elements, from registers + 2 LDS edge scalars
        {
            const float4 a0 = yc[0][0], a1 = yc[0][1], a2 = yc[0][2];
            const float4 p0 = yc[1][0], p1 = yc[1][1], p2 = yc[1][2];
            GTERM(a0.y - wlY , p0.y - wlP , s2w0);
            GTERM(a0.z - a0.x, p0.z - p0.x, 0.25f);
            GTERM(a0.w - a0.y, p0.w - p0.y, 0.25f);
            GTERM(a1.x - a0.z, p1.x - p0.z, 0.25f);
            GTERM(a1.y - a0.w, p1.y - p0.w, 0.25f);
            GTERM(a1.z - a1.x, p1.z - p1.x, 0.25f);
            GTERM(a1.w - a1.y, p1.w - p1.y, 0.25f);
            GTERM(a2.x - a1.z, p2.x - p1.z, 0.25f);
            GTERM(a2.y - a1.w, p2.y - p1.w, 0.25f);
            GTERM(a2.z - a2.x, p2.z - p2.x, 0.25f);
            GTERM(a2.w - a2.y, p2.w - p2.y, 0.25f);
            GTERM(wrY  - a2.z, wrP  - p2.z, s2w3);
        }
        // shift register D-pipeline
        #pragma unroll
        for (int g = 0; g < 3; ++g) {
            ym[0][g] = yc[0][g]; ym[1][g] = yc[1][g];
            yc[0][g] = cn[0][g]; yc[1][g] = cn[1][g];
        }
        cur = nx;
    }

    // ---- wave reduction (single wave): lane 0 writes the block partials ----
    #pragma unroll
    for (int off = 32; off > 0; off >>= 1) {
        l1 += __shfl_down(l1, off, 64);
        gd += __shfl_down(gd, off, 64);
    }
    if (lane == 0) {
        part[2 * blk0]     = l1;
        part[2 * blk0 + 1] = gd;
    }
}

// Reduce per-block partials + BCE over the small discriminator tensor.
__global__ __launch_bounds__(BLOCKF) void finalize_kernel(const float* __restrict__ dsc,
                                                          const float* __restrict__ part,
                                                          float* __restrict__ out) {
    float l1 = 0.f, gd = 0.f, s = 0.f;
    for (int i = threadIdx.x; i < GRIDV; i += BLOCKF) {
        l1 += part[2 * i];
        gd += part[2 * i + 1];
    }
    for (int i = threadIdx.x; i < NDSC; i += BLOCKF) {
        const float x = dsc[i];
        // target is zeros: max(x,0) - x*0 + log1p(exp(-|x|))
        s += fmaxf(x, 0.f) + log1pf(expf(-fabsf(x)));
    }
    __shared__ float a[4], c[4], e2[4];
    #pragma unroll
    for (int off = 32; off > 0; off >>= 1) {
        l1 += __shfl_down(l1, off, 64);
        gd += __shfl_down(gd, off, 64);
        s  += __shfl_down(s,  off, 64);
    }
    if ((threadIdx.x & 63) == 0) {
        const int w = threadIdx.x >> 6;
        a[w] = l1; c[w] = gd; e2[w] = s;
    }
    __syncthreads();
    if (threadIdx.x == 0) {
        const float bce = (e2[0] + e2[1] + e2[2] + e2[3]) / (float)NDSC;
        const float l1m = (a[0] + a[1] + a[2] + a[3]) / (float)NTOT;
        const float gdm = (c[0] + c[1] + c[2] + c[3]) / (float)NTOT;
        out[0] = bce + 100.f * (l1m + gdm);
    }
}

extern "C" void kernel_launch(void* const* d_in, const int* in_sizes, int n_in,
                              void* d_out, int out_size, void* d_ws, size_t ws_size,
                              hipStream_t stream) {
    const float* dsc_fake = (const float*)d_in[0];
    const float* predicts = (const float*)d_in[1];
    const float* y_data   = (const float*)d_in[2];
    // d_in[3] (zeros) unused: target==0 makes the -x*target term vanish.
    float* part = (float*)d_ws;   // GRIDV*2 floats, fully overwritten each call
    float* out  = (float*)d_out;

    vol_kernel<<<GRIDV, BLOCKV, 0, stream>>>(predicts, y_data, part);
    finalize_kernel<<<1, BLOCKF, 0, stream>>>(dsc_fake, part, out);
}